// Round 11
// baseline (271.653 us; speedup 1.0000x reference)
//
#include <hip/hip_runtime.h>
#include <hip/hip_fp8.h>
#include <cstdint>

typedef float f32x4 __attribute__((ext_vector_type(4)));
typedef int i32x8 __attribute__((ext_vector_type(8)));
typedef long long i64;

static constexpr int Mdim = 8192;
static constexpr int Kdim = 4096;
static constexpr int Ndim = 4096;

// ---- 256^2 tile, A-only LDS (dbuf), B packed + cross-tile reg prefetch ----
static constexpr int BM = 256, BN = 256, BK = 128;  // BK in fp8 bytes
static constexpr int NT = Kdim / BK;                // 32 K-tiles
static constexpr int NWG_M = Mdim / BM;             // 32
static constexpr int NWG_N = Ndim / BN;             // 16
static constexpr int NWG = NWG_M * NWG_N;           // 512

// Packed-B layout (round-10-verified): uint4 index
//   o = (((rb*32 + kt)*2 + h)*4 + kq)*16 + r15
// GEMM read: p = PB + (rb*32+kt)*2048 + lane*16, halves at p, p+1024.

// ---------------------------------------------------------------------------
__device__ __forceinline__ uint8_t f32_to_e4m3(float f) {
  return (uint8_t)__hip_cvt_float_to_fp8(f, __HIP_SATFINITE, __HIP_E4M3);
}

__device__ __forceinline__ uint4 cvt16(const float4 f0, const float4 f1,
                                       const float4 f2, const float4 f3) {
  const float v[16] = {f0.x, f0.y, f0.z, f0.w, f1.x, f1.y, f1.z, f1.w,
                       f2.x, f2.y, f2.z, f2.w, f3.x, f3.y, f3.z, f3.w};
  union alignas(16) {
    uint32_t u[4];
    uint8_t b[16];
    uint4 q;
  } r;
#pragma unroll
  for (int j = 0; j < 16; ++j) r.b[j] = f32_to_e4m3(v[j]);
  return r.q;
}

__global__ __launch_bounds__(256) void quant_fp8_kernel(
    const float* __restrict__ in, uint8_t* __restrict__ out, int n_vec16) {
  const int stride = gridDim.x * blockDim.x;
  for (int i = blockIdx.x * blockDim.x + threadIdx.x; i < n_vec16; i += stride) {
    const float4* src = reinterpret_cast<const float4*>(in) + (size_t)i * 4;
    reinterpret_cast<uint4*>(out)[i] = cvt16(src[0], src[1], src[2], src[3]);
  }
}

// Coalesced pack: each 128-thread half-block emits one (rb,kt) = contiguous
// 2KB output. thread j: r15=j&15, kq=(j>>4)&3, h=j>>6; reads 64B contiguous.
__global__ __launch_bounds__(256) void quant_pack_w_kernel(
    const float* __restrict__ W, uint8_t* __restrict__ PB) {
  const int pair = blockIdx.x * 2 + ((int)threadIdx.x >> 7);  // 0..8191
  const int j = (int)threadIdx.x & 127;
  const int rb = pair >> 5;   // 0..255
  const int kt = pair & 31;   // 0..31
  const int r15 = j & 15, kq = (j >> 4) & 3, h = j >> 6;
  const int g = rb * 16 + r15;
  const float4* src = reinterpret_cast<const float4*>(
      W + (size_t)g * Kdim + kt * 128 + kq * 32 + h * 16);
  const size_t o = (((size_t)(rb * 32 + kt) * 2 + h) * 4 + kq) * 16 + r15;
  reinterpret_cast<uint4*>(PB)[o] = cvt16(src[0], src[1], src[2], src[3]);
}

__device__ __forceinline__ void gload_lds16(const uint8_t* g, uint8_t* l) {
  __builtin_amdgcn_global_load_lds(
      (const __attribute__((address_space(1))) void*)g,
      (__attribute__((address_space(3))) void*)l, 16, 0, 0);
}

__device__ __forceinline__ f32x4 mx_mfma(i32x8 a, i32x8 b, f32x4 c) {
  // fp8 e4m3 A/B, unit e8m0 scales (0x7f) -> identical to non-scaled fp8.
  return __builtin_amdgcn_mfma_scale_f32_16x16x128_f8f6f4(
      a, b, c, 0, 0, 0, 0x7f7f7f7f, 0, 0x7f7f7f7f);
}

// ---------------------------------------------------------------------------
// Round 11: latency-bound fix. All ~170us kernels consumed vmem results
// issued <1 phase earlier (exposed 200-900cy per tile, lockstep waves).
// Now every vmem consumer sits >= half a tile behind its issue:
//  - B frags: n-pair-major MFMA order -> bf01 die after phase X, refilled
//    in place for kt+1 (cover ~2000cy); bf23 refilled at tile end (cover
//    ~3000cy, consumed at kt+1 phase Y).
//  - A stage: issued at kt top into buf[c^1], consumed at kt+1 (round-10
//    hazard argument: vmcnt(4) retires stage, barrier publishes; stage is
//    oldest of the 8 in-flight vmem -> vmcnt(4) leaves the 4 B-loads fly).
// ---------------------------------------------------------------------------
__global__ __launch_bounds__(512, 2) void gemm_fp8_mx_pf(
    const uint8_t* __restrict__ Aq, const uint8_t* __restrict__ PB,
    const float* __restrict__ bias, const float* __restrict__ sa,
    const float* __restrict__ sb, float* __restrict__ C) {
  __shared__ alignas(16) uint8_t sA[2][BM * BK];  // 2 x 32 KiB (A only)

  const int wg = (int)blockIdx.x;
  const int xcd = wg & 7;
  const int within = wg >> 3;                      // 0..63
  const int bn0 = (xcd * 2 + (within >> 5)) * BN;  // XCD-pinned B panels
  const int bm0 = (within & 31) * BM;

  const int t = (int)threadIdx.x;  // 0..511
  const int lane = t & 63;
  const int wave = t >> 6;
  const int wm = wave >> 2;  // 0..1
  const int wn = wave & 3;   // 0..3

  // ---- A staging (round-2-verified swizzle): 4 calls x 512 thr x 16 B.
  const int srow = t >> 3;
  const int sc16 = (t & 7) ^ (srow & 7);
  const uint8_t* aBase = Aq + (size_t)(bm0 + srow) * Kdim + sc16 * 16;
  const int ldsOff = t * 16;

  auto stageA = [&](int buf, int kt) {
    const size_t kb = (size_t)kt * BK;
#pragma unroll
    for (int i = 0; i < 4; ++i)
      gload_lds16(aBase + kb + (size_t)(i * 64) * Kdim,
                  &sA[buf][i * 8192 + ldsOff]);
  };

  // ---- A fragment reads from LDS
  const int r7 = lane & 7;
  const int kg = (lane >> 4) * 2;
  const int off0 = (kg ^ r7) * 16;
  const int off1 = ((kg + 1) ^ r7) * 16;
  const int rbA = (wm * 128 + (lane & 15)) * BK;

  auto ldfrag = [&](const uint8_t* base) -> i32x8 {
    union {
      i32x8 v;
      int4 h[2];
    } u;
    u.h[0] = *reinterpret_cast<const int4*>(base + off0);
    u.h[1] = *reinterpret_cast<const int4*>(base + off1);
    return u.v;
  };

  // ---- B fragments from packed layout (coalesced: base + lane*16)
  const int rbB0 = (bn0 >> 4) + wn * 4;  // row-block of frag n=0
  auto ldb = [&](int n, int kt) -> i32x8 {
    const uint8_t* p = PB + ((size_t)((rbB0 + n) * 32 + kt) * 2048) + lane * 16;
    union {
      i32x8 v;
      int4 h[2];
    } u;
    u.h[0] = *reinterpret_cast<const int4*>(p);
    u.h[1] = *reinterpret_cast<const int4*>(p + 1024);
    return u.v;
  };

  f32x4 acc[8][4] = {};

  // ---- prologue: A(0) staged + B(0) frags loaded; drain; publish.
  stageA(0, 0);
  i32x8 bf0 = ldb(0, 0);
  i32x8 bf1 = ldb(1, 0);
  i32x8 bf2 = ldb(2, 0);
  i32x8 bf3 = ldb(3, 0);
  asm volatile("s_waitcnt vmcnt(0)" ::: "memory");
  __builtin_amdgcn_s_barrier();

#pragma unroll 1
  for (int kt = 0; kt < NT; ++kt) {
    const int c = kt & 1;
    const uint8_t* A = &sA[c][0];
    const bool more = (kt + 1 < NT);

    // stage A(kt+1) FIRST (oldest vmem of this tile)
    if (more) stageA(c ^ 1, kt + 1);

    // ---- phase X: n = 0,1 (bf0,bf1 loaded mid-tile kt-1; cover >= 1/2 tile)
    i32x8 a0 = ldfrag(A + rbA + 0 * 16 * BK);
    i32x8 a1 = ldfrag(A + rbA + 1 * 16 * BK);
    i32x8 a2 = ldfrag(A + rbA + 2 * 16 * BK);
    i32x8 a3 = ldfrag(A + rbA + 3 * 16 * BK);
    __builtin_amdgcn_s_setprio(1);
    acc[0][0] = mx_mfma(a0, bf0, acc[0][0]);
    acc[0][1] = mx_mfma(a0, bf1, acc[0][1]);
    acc[1][0] = mx_mfma(a1, bf0, acc[1][0]);
    acc[1][1] = mx_mfma(a1, bf1, acc[1][1]);
    __builtin_amdgcn_s_setprio(0);
    i32x8 a4 = ldfrag(A + rbA + 4 * 16 * BK);
    i32x8 a5 = ldfrag(A + rbA + 5 * 16 * BK);
    __builtin_amdgcn_s_setprio(1);
    acc[2][0] = mx_mfma(a2, bf0, acc[2][0]);
    acc[2][1] = mx_mfma(a2, bf1, acc[2][1]);
    acc[3][0] = mx_mfma(a3, bf0, acc[3][0]);
    acc[3][1] = mx_mfma(a3, bf1, acc[3][1]);
    __builtin_amdgcn_s_setprio(0);
    i32x8 a6 = ldfrag(A + rbA + 6 * 16 * BK);
    i32x8 a7 = ldfrag(A + rbA + 7 * 16 * BK);
    __builtin_amdgcn_s_setprio(1);
    acc[4][0] = mx_mfma(a4, bf0, acc[4][0]);
    acc[4][1] = mx_mfma(a4, bf1, acc[4][1]);
    acc[5][0] = mx_mfma(a5, bf0, acc[5][0]);
    acc[5][1] = mx_mfma(a5, bf1, acc[5][1]);
    acc[6][0] = mx_mfma(a6, bf0, acc[6][0]);
    acc[6][1] = mx_mfma(a6, bf1, acc[6][1]);
    acc[7][0] = mx_mfma(a7, bf0, acc[7][0]);
    acc[7][1] = mx_mfma(a7, bf1, acc[7][1]);
    __builtin_amdgcn_s_setprio(0);

    // bf0,bf1 dead -> refill in place for kt+1 (consumed next phase X)
    if (more) {
      bf0 = ldb(0, kt + 1);
      bf1 = ldb(1, kt + 1);
    }

    // ---- phase Y: n = 2,3 (bf2,bf3 loaded at END of kt-1; cover ~full tile)
    __builtin_amdgcn_s_setprio(1);
    acc[0][2] = mx_mfma(a0, bf2, acc[0][2]);
    acc[0][3] = mx_mfma(a0, bf3, acc[0][3]);
    acc[1][2] = mx_mfma(a1, bf2, acc[1][2]);
    acc[1][3] = mx_mfma(a1, bf3, acc[1][3]);
    acc[2][2] = mx_mfma(a2, bf2, acc[2][2]);
    acc[2][3] = mx_mfma(a2, bf3, acc[2][3]);
    acc[3][2] = mx_mfma(a3, bf2, acc[3][2]);
    acc[3][3] = mx_mfma(a3, bf3, acc[3][3]);
    acc[4][2] = mx_mfma(a4, bf2, acc[4][2]);
    acc[4][3] = mx_mfma(a4, bf3, acc[4][3]);
    acc[5][2] = mx_mfma(a5, bf2, acc[5][2]);
    acc[5][3] = mx_mfma(a5, bf3, acc[5][3]);
    acc[6][2] = mx_mfma(a6, bf2, acc[6][2]);
    acc[6][3] = mx_mfma(a6, bf3, acc[6][3]);
    acc[7][2] = mx_mfma(a7, bf2, acc[7][2]);
    acc[7][3] = mx_mfma(a7, bf3, acc[7][3]);
    __builtin_amdgcn_s_setprio(0);

    if (more) {
      // bf2,bf3 dead -> refill for kt+1 (consumed next phase Y)
      bf2 = ldb(2, kt + 1);
      bf3 = ldb(3, kt + 1);
      // in flight (oldest first): stageA(kt+1) x4, bf01 x2, bf23 x2.
      // vmcnt(4): stage retired; the 4 B-loads stay flying across barrier.
      asm volatile("s_waitcnt vmcnt(4)" ::: "memory");
      __builtin_amdgcn_s_barrier();
    }
  }

  // ---- epilogue (C/D: col = lane&15, row = (lane>>4)*4 + reg)
  const float scale = sa[0] * sb[0];
  const int orow0 = bm0 + wm * 128 + ((lane >> 4) << 2);
  const int ocol0 = bn0 + wn * 64 + (lane & 15);
#pragma unroll
  for (int n = 0; n < 4; ++n) {
    const int col = ocol0 + n * 16;
    const float bv = bias[col];
#pragma unroll
    for (int m = 0; m < 8; ++m) {
      const int row = orow0 + m * 16;
#pragma unroll
      for (int r = 0; r < 4; ++r)
        C[(size_t)(row + r) * Ndim + col] = acc[m][n][r] * scale + bv;
    }
  }
}

// ---------------------------------------------------------------------------
// Fallback (tiny d_ws only): round-1 fused kernel, known-correct.
// ---------------------------------------------------------------------------
__device__ __forceinline__ void stage16_cvt(const float* g, uint8_t* l) {
  const float4* s = reinterpret_cast<const float4*>(g);
  uint4 q = cvt16(s[0], s[1], s[2], s[3]);
  *reinterpret_cast<uint4*>(l) = q;
}

__global__ __launch_bounds__(256) void gemm_fp8_fused_kernel(
    const float* __restrict__ X, const float* __restrict__ W,
    const float* __restrict__ bias, const float* __restrict__ sa,
    const float* __restrict__ sb, float* __restrict__ C) {
  constexpr int FBM = 128, FBN = 128, FBK = 64;
  constexpr int FNWG_N = Ndim / FBN;
  __shared__ alignas(16) uint8_t As[FBM * FBK];
  __shared__ alignas(16) uint8_t Bs[FBN * FBK];

  int wg = (int)blockIdx.x;
  const int nwg = (Mdim / FBM) * FNWG_N;
  wg = (wg & 7) * (nwg / 8) + (wg >> 3);
  const int bm0 = (wg / FNWG_N) * FBM;
  const int bn0 = (wg % FNWG_N) * FBN;

  const int t = (int)threadIdx.x;
  const int lane = t & 63;
  const int wave = t >> 6;
  const int wm = wave >> 1, wn = wave & 1;

  const int c0 = t, c1 = t + 256;
  const int r0 = c0 >> 2, col0 = (c0 & 3) * 16;
  const int r1 = c1 >> 2, col1 = (c1 & 3) * 16;
  const float* xa0 = X + (size_t)(bm0 + r0) * Kdim + col0;
  const float* xa1 = X + (size_t)(bm0 + r1) * Kdim + col1;
  const float* wb0 = W + (size_t)(bn0 + r0) * Kdim + col0;
  const float* wb1 = W + (size_t)(bn0 + r1) * Kdim + col1;

  const int arow = (wm * 64 + (lane & 15)) * FBK;
  const int brow = (wn * 64 + (lane & 15)) * FBK;
  const int koff = (lane >> 4) * 8;

  f32x4 acc[4][4] = {};

  for (int kt = 0; kt < Kdim / FBK; ++kt) {
    const int kb = kt * FBK;
    stage16_cvt(xa0 + kb, As + c0 * 16);
    stage16_cvt(xa1 + kb, As + c1 * 16);
    stage16_cvt(wb0 + kb, Bs + c0 * 16);
    stage16_cvt(wb1 + kb, Bs + c1 * 16);
    __syncthreads();
#pragma unroll
    for (int kk = 0; kk < FBK / 32; ++kk) {
      i64 a[4], b[4];
#pragma unroll
      for (int m = 0; m < 4; ++m)
        a[m] = *reinterpret_cast<const i64*>(&As[arow + m * 16 * FBK + kk * 32 + koff]);
#pragma unroll
      for (int n = 0; n < 4; ++n)
        b[n] = *reinterpret_cast<const i64*>(&Bs[brow + n * 16 * FBK + kk * 32 + koff]);
#pragma unroll
      for (int m = 0; m < 4; ++m)
#pragma unroll
        for (int n = 0; n < 4; ++n)
          acc[m][n] = __builtin_amdgcn_mfma_f32_16x16x32_fp8_fp8(
              a[m], b[n], acc[m][n], 0, 0, 0);
    }
    __syncthreads();
  }

  const float scale = sa[0] * sb[0];
  const int orow0 = bm0 + wm * 64 + ((lane >> 4) << 2);
  const int ocol0 = bn0 + wn * 64 + (lane & 15);
#pragma unroll
  for (int n = 0; n < 4; ++n) {
    const int col = ocol0 + n * 16;
    const float bv = bias[col];
#pragma unroll
    for (int m = 0; m < 4; ++m) {
      const int row = orow0 + m * 16;
#pragma unroll
      for (int r = 0; r < 4; ++r)
        C[(size_t)(row + r) * Ndim + col] = acc[m][n][r] * scale + bv;
    }
  }
}

// ---------------------------------------------------------------------------
extern "C" void kernel_launch(void* const* d_in, const int* in_sizes, int n_in,
                              void* d_out, int out_size, void* d_ws, size_t ws_size,
                              hipStream_t stream) {
  const float* x = (const float*)d_in[0];      // [M, K]
  const float* w = (const float*)d_in[1];      // [N, K]
  const float* bias = (const float*)d_in[2];   // [N]
  const float* s_in = (const float*)d_in[3];   // scalar
  const float* s_w = (const float*)d_in[4];    // scalar
  float* out = (float*)d_out;                  // [M, N] fp32

  const size_t needA = (size_t)Mdim * Kdim;  // 32 MiB
  const size_t needB = (size_t)Ndim * Kdim;  // 16 MiB (packed)

  if (ws_size >= needA + needB) {
    uint8_t* Aq = (uint8_t*)d_ws;
    uint8_t* PB = Aq + needA;
    quant_fp8_kernel<<<2048, 256, 0, stream>>>(x, Aq, (int)(needA / 16));
    quant_pack_w_kernel<<<4096, 256, 0, stream>>>(w, PB);
    gemm_fp8_mx_pf<<<NWG, 512, 0, stream>>>(Aq, PB, bias, s_in, s_w, out);
  } else {
    gemm_fp8_fused_kernel<<<(Mdim / 128) * (Ndim / 128), 256, 0, stream>>>(
        x, w, bias, s_in, s_w, out);
  }
}